// Round 1
// baseline (4646.551 us; speedup 1.0000x reference)
//
#include <hip/hip_runtime.h>
#include <hip/hip_bf16.h>

// Problem constants (fixed by reference)
#define T_STEPS 256
#define BATCH   16
#define HID     512
#define VOCAB   32000
#define M_TOT   (T_STEPS * BATCH)   // 4096

typedef __attribute__((ext_vector_type(8))) short s8v;   // 8 bf16 (4 VGPRs)
typedef __attribute__((ext_vector_type(4))) float f4v;   // 4 f32 accum

__device__ __forceinline__ unsigned short f2bf_rne(float f) {
  unsigned u = __float_as_uint(f);
  unsigned r = u + 0x7fffu + ((u >> 16) & 1u);
  return (unsigned short)(r >> 16);
}
__device__ __forceinline__ float bf2f(unsigned short s) {
  return __uint_as_float(((unsigned)s) << 16);
}

// ---------------------------------------------------------------------------
// K1: pre[m][i] = b1[i] + sum_j emb[tok[m]][j] * w1[i][j]   (wx part of w1)
// Split-bf16 MFMA GEMM, 128x128 tile, BK=32, 256 threads (2x2 waves of 64x64).
// ---------------------------------------------------------------------------
__global__ __launch_bounds__(256, 2) void pre_gemm_kernel(
    const int* __restrict__ tok, const float* __restrict__ emb,
    const float* __restrict__ w1, const float* __restrict__ b1,
    float* __restrict__ pre) {
  __shared__ s8v Ah[512], Al[512], Bh[512], Bl[512];  // [row 0..127][kg 0..3]
  const int mt = blockIdx.x, nt = blockIdx.y;
  const int tid = threadIdx.x;
  const int lane = tid & 63, wave = tid >> 6;
  const int wm = wave >> 1, wn = wave & 1;
  const int m0 = mt * 128, n0 = nt * 128;
  f4v acc[4][4] = {};

  for (int ks = 0; ks < 16; ++ks) {
    const int k0 = ks * 32;
#pragma unroll
    for (int c = 0; c < 2; ++c) {
      int idx = c * 256 + tid;            // 0..511
      int r = idx >> 2, kg = idx & 3;
      int kgp = kg ^ (r & 3);
      // ---- A: gather emb row, split f32 -> hi/lo bf16
      int t_ = tok[m0 + r];
      const float* as = emb + (size_t)t_ * HID + k0 + kg * 8;
      float4 a0 = *(const float4*)as;
      float4 a1 = *(const float4*)(as + 4);
      float av[8] = {a0.x, a0.y, a0.z, a0.w, a1.x, a1.y, a1.z, a1.w};
      s8v ah, al;
#pragma unroll
      for (int j = 0; j < 8; ++j) {
        unsigned short h = f2bf_rne(av[j]);
        ah[j] = (short)h;
        al[j] = (short)f2bf_rne(av[j] - bf2f(h));
      }
      Ah[r * 4 + kgp] = ah;  Al[r * 4 + kgp] = al;
      // ---- B: w1 row (wx part), row stride 1024 f32
      const float* bs = w1 + (size_t)(n0 + r) * 1024 + k0 + kg * 8;
      float4 b0 = *(const float4*)bs;
      float4 b1v = *(const float4*)(bs + 4);
      float bv[8] = {b0.x, b0.y, b0.z, b0.w, b1v.x, b1v.y, b1v.z, b1v.w};
      s8v bh, bl;
#pragma unroll
      for (int j = 0; j < 8; ++j) {
        unsigned short h = f2bf_rne(bv[j]);
        bh[j] = (short)h;
        bl[j] = (short)f2bf_rne(bv[j] - bf2f(h));
      }
      Bh[r * 4 + kgp] = bh;  Bl[r * 4 + kgp] = bl;
    }
    __syncthreads();
    s8v afh[4], afl[4], bfh[4], bfl[4];
#pragma unroll
    for (int f = 0; f < 4; ++f) {
      int rA = wm * 64 + f * 16 + (lane & 15);
      afh[f] = Ah[rA * 4 + ((lane >> 4) ^ (rA & 3))];
      afl[f] = Al[rA * 4 + ((lane >> 4) ^ (rA & 3))];
      int rB = wn * 64 + f * 16 + (lane & 15);
      bfh[f] = Bh[rB * 4 + ((lane >> 4) ^ (rB & 3))];
      bfl[f] = Bl[rB * 4 + ((lane >> 4) ^ (rB & 3))];
    }
#pragma unroll
    for (int i = 0; i < 4; ++i)
#pragma unroll
      for (int j = 0; j < 4; ++j) {
        acc[i][j] = __builtin_amdgcn_mfma_f32_16x16x32_bf16(afh[i], bfh[j], acc[i][j], 0, 0, 0);
        acc[i][j] = __builtin_amdgcn_mfma_f32_16x16x32_bf16(afl[i], bfh[j], acc[i][j], 0, 0, 0);
        acc[i][j] = __builtin_amdgcn_mfma_f32_16x16x32_bf16(afh[i], bfl[j], acc[i][j], 0, 0, 0);
      }
    __syncthreads();
  }
#pragma unroll
  for (int j = 0; j < 4; ++j) {
    int col = n0 + wn * 64 + j * 16 + (lane & 15);
    float bias = b1[col];
#pragma unroll
    for (int i = 0; i < 4; ++i)
#pragma unroll
      for (int rg = 0; rg < 4; ++rg) {
        int row = m0 + wm * 64 + i * 16 + (lane >> 4) * 4 + rg;
        pre[(size_t)row * HID + col] = acc[i][j][rg] + bias;
      }
  }
}

// ---------------------------------------------------------------------------
// K2: persistent scan. 64 WGs = 16 b x 4 i-groups, 512 threads each.
// Thread (i_loc, q) holds wh[i][q*128 .. +128] in 128 VGPRs (loaded once).
// h exchanged via volatile global double buffer; 4-party barrier per b per step.
// ---------------------------------------------------------------------------
__global__ __launch_bounds__(512, 2) void scan_kernel(
    const float* __restrict__ w1, const float* __restrict__ pre,
    float* hbuf, int* cnt,
    unsigned short* __restrict__ o_hi, unsigned short* __restrict__ o_lo,
    float* __restrict__ h_last_out) {
  const int wg = blockIdx.x;
  const int b = wg >> 2, ig = wg & 3;
  const int tid = threadIdx.x;
  const int il = tid & 127, q = tid >> 7;
  const int i = ig * 128 + il;

  // load wh slice into registers (wh[i][j] = w1[i*1024 + 512 + j])
  float w[128];
  const float4* wrow4 = (const float4*)(w1 + (size_t)i * 1024 + 512 + q * 128);
#pragma unroll
  for (int j4 = 0; j4 < 32; ++j4) {
    float4 v = wrow4[j4];
    w[j4 * 4 + 0] = v.x; w[j4 * 4 + 1] = v.y;
    w[j4 * 4 + 2] = v.z; w[j4 * 4 + 3] = v.w;
  }

  __shared__ float hs[512];
  __shared__ float part[4][128];
  volatile float* hb = hbuf;

  for (int t = 0; t < T_STEPS; ++t) {
    const int cur = t & 1, nxt = cur ^ 1;
    hs[tid] = hb[cur * (BATCH * HID) + b * HID + tid];   // coherent read
    __syncthreads();
    float p = 0.f;
#pragma unroll
    for (int j = 0; j < 128; ++j) p += w[j] * hs[q * 128 + j];
    part[q][il] = p;
    __syncthreads();
    if (tid < 128) {
      float s = part[0][tid] + part[1][tid] + part[2][tid] + part[3][tid];
      int m = t * BATCH + b;
      s += pre[(size_t)m * HID + ig * 128 + tid];
      float hn = tanhf(s);
      hb[nxt * (BATCH * HID) + b * HID + ig * 128 + tid] = hn;  // coherent write
      unsigned short hi = f2bf_rne(hn);
      o_hi[(size_t)m * HID + ig * 128 + tid] = hi;
      o_lo[(size_t)m * HID + ig * 128 + tid] = f2bf_rne(hn - bf2f(hi));
      if (t == T_STEPS - 1) h_last_out[b * HID + ig * 128 + tid] = hn;
    }
    __syncthreads();
    __threadfence();
    if (tid == 0) {
      atomicAdd(&cnt[b * 16], 1);
      const int target = 4 * (t + 1);
      long spins = 0;
      while (atomicAdd(&cnt[b * 16], 0) < target) {
        __builtin_amdgcn_s_sleep(8);
        if (++spins > 100000000L) break;  // safety: never hang the harness
      }
    }
    __syncthreads();
    __threadfence();
  }
}

// ---------------------------------------------------------------------------
// K3: logits[m][v] = dec_b[v] + sum_j outputs[m][j] * dec_w[v][j]
// A = o_hi/o_lo (bf16, from scan), B = dec_w f32 split on the fly.
// ---------------------------------------------------------------------------
__global__ __launch_bounds__(256, 2) void dec_gemm_kernel(
    const unsigned short* __restrict__ o_hi, const unsigned short* __restrict__ o_lo,
    const float* __restrict__ dec_w, const float* __restrict__ dec_b,
    float* __restrict__ out) {
  __shared__ s8v Ah[512], Al[512], Bh[512], Bl[512];
  const int mt = blockIdx.x;   // 0..31   (x fastest -> consecutive blocks share B tile)
  const int nt = blockIdx.y;   // 0..249
  const int tid = threadIdx.x;
  const int lane = tid & 63, wave = tid >> 6;
  const int wm = wave >> 1, wn = wave & 1;
  const int m0 = mt * 128, n0 = nt * 128;
  f4v acc[4][4] = {};

  for (int ks = 0; ks < 16; ++ks) {
    const int k0 = ks * 32;
#pragma unroll
    for (int c = 0; c < 2; ++c) {
      int idx = c * 256 + tid;
      int r = idx >> 2, kg = idx & 3;
      int kgp = kg ^ (r & 3);
      // ---- A: already-split bf16, direct 16B copies
      size_t aoff = (size_t)(m0 + r) * HID + k0 + kg * 8;
      Ah[r * 4 + kgp] = *(const s8v*)(o_hi + aoff);
      Al[r * 4 + kgp] = *(const s8v*)(o_lo + aoff);
      // ---- B: dec_w f32 -> hi/lo
      const float* bs = dec_w + (size_t)(n0 + r) * HID + k0 + kg * 8;
      float4 b0 = *(const float4*)bs;
      float4 b1v = *(const float4*)(bs + 4);
      float bv[8] = {b0.x, b0.y, b0.z, b0.w, b1v.x, b1v.y, b1v.z, b1v.w};
      s8v bh, bl;
#pragma unroll
      for (int j = 0; j < 8; ++j) {
        unsigned short h = f2bf_rne(bv[j]);
        bh[j] = (short)h;
        bl[j] = (short)f2bf_rne(bv[j] - bf2f(h));
      }
      Bh[r * 4 + kgp] = bh;  Bl[r * 4 + kgp] = bl;
    }
    __syncthreads();
    s8v afh[4], afl[4], bfh[4], bfl[4];
#pragma unroll
    for (int f = 0; f < 4; ++f) {
      int rA = wm * 64 + f * 16 + (lane & 15);
      afh[f] = Ah[rA * 4 + ((lane >> 4) ^ (rA & 3))];
      afl[f] = Al[rA * 4 + ((lane >> 4) ^ (rA & 3))];
      int rB = wn * 64 + f * 16 + (lane & 15);
      bfh[f] = Bh[rB * 4 + ((lane >> 4) ^ (rB & 3))];
      bfl[f] = Bl[rB * 4 + ((lane >> 4) ^ (rB & 3))];
    }
#pragma unroll
    for (int i = 0; i < 4; ++i)
#pragma unroll
      for (int j = 0; j < 4; ++j) {
        acc[i][j] = __builtin_amdgcn_mfma_f32_16x16x32_bf16(afh[i], bfh[j], acc[i][j], 0, 0, 0);
        acc[i][j] = __builtin_amdgcn_mfma_f32_16x16x32_bf16(afl[i], bfh[j], acc[i][j], 0, 0, 0);
        acc[i][j] = __builtin_amdgcn_mfma_f32_16x16x32_bf16(afh[i], bfl[j], acc[i][j], 0, 0, 0);
      }
    __syncthreads();
  }
#pragma unroll
  for (int j = 0; j < 4; ++j) {
    int col = n0 + wn * 64 + j * 16 + (lane & 15);
    float bias = dec_b[col];
#pragma unroll
    for (int i = 0; i < 4; ++i)
#pragma unroll
      for (int rg = 0; rg < 4; ++rg) {
        int row = m0 + wm * 64 + i * 16 + (lane >> 4) * 4 + rg;
        out[(size_t)row * VOCAB + col] = acc[i][j][rg] + bias;
      }
  }
}

// ---------------------------------------------------------------------------
// Workspace layout (bytes):
//   [0,        65536)   hbuf: 2 x 16 x 512 f32   (zeroed each call)
//   [65536,    66560)   cnt : 16 counters, 64B apart (zeroed each call)
//   [1 MiB,    9 MiB)   pre : 4096 x 512 f32
//   [16 MiB,  20 MiB)   o_hi: 4096 x 512 bf16
//   [20 MiB,  24 MiB)   o_lo: 4096 x 512 bf16
// ---------------------------------------------------------------------------
extern "C" void kernel_launch(void* const* d_in, const int* in_sizes, int n_in,
                              void* d_out, int out_size, void* d_ws, size_t ws_size,
                              hipStream_t stream) {
  (void)in_sizes; (void)n_in; (void)out_size; (void)ws_size;
  const int*   tok   = (const int*)d_in[0];
  const float* emb   = (const float*)d_in[2];
  const float* w1    = (const float*)d_in[3];
  const float* b1    = (const float*)d_in[4];
  const float* dec_w = (const float*)d_in[5];
  const float* dec_b = (const float*)d_in[6];
  char* ws = (char*)d_ws;
  float* hbuf = (float*)(ws);
  int*   cnt  = (int*)(ws + 65536);
  float* pre  = (float*)(ws + (1u << 20));
  unsigned short* o_hi = (unsigned short*)(ws + 16u * (1u << 20));
  unsigned short* o_lo = (unsigned short*)(ws + 20u * (1u << 20));
  float* out = (float*)d_out;

  hipMemsetAsync(ws, 0, 66560, stream);
  pre_gemm_kernel<<<dim3(32, 4), dim3(256), 0, stream>>>(tok, emb, w1, b1, pre);
  scan_kernel<<<dim3(64), dim3(512), 0, stream>>>(
      w1, pre, hbuf, cnt, o_hi, o_lo, out + (size_t)M_TOT * VOCAB);
  dec_gemm_kernel<<<dim3(32, 250), dim3(256), 0, stream>>>(o_hi, o_lo, dec_w, dec_b, out);
}

// Round 2
// 1610.636 us; speedup vs baseline: 2.8849x; 2.8849x over previous
//
#include <hip/hip_runtime.h>
#include <hip/hip_bf16.h>

// Problem constants (fixed by reference)
#define T_STEPS 256
#define BATCH   16
#define HID     512
#define VOCAB   32000
#define M_TOT   (T_STEPS * BATCH)   // 4096

typedef __attribute__((ext_vector_type(8))) short s8v;   // 8 bf16 (4 VGPRs)
typedef __attribute__((ext_vector_type(4))) float f4v;   // 4 f32 accum

__device__ __forceinline__ unsigned short f2bf_rne(float f) {
  unsigned u = __float_as_uint(f);
  unsigned r = u + 0x7fffu + ((u >> 16) & 1u);
  return (unsigned short)(r >> 16);
}
__device__ __forceinline__ float bf2f(unsigned short s) {
  return __uint_as_float(((unsigned)s) << 16);
}

// ---------------------------------------------------------------------------
// K1: pre[m][i] = b1[i] + sum_j emb[tok[m]][j] * w1[i][j]   (wx part of w1)
// Split-bf16 MFMA GEMM, 128x128 tile, BK=32, 256 threads (2x2 waves of 64x64).
// (unchanged from round 1 — passed, ~small cost)
// ---------------------------------------------------------------------------
__global__ __launch_bounds__(256, 2) void pre_gemm_kernel(
    const int* __restrict__ tok, const float* __restrict__ emb,
    const float* __restrict__ w1, const float* __restrict__ b1,
    float* __restrict__ pre) {
  __shared__ s8v Ah[512], Al[512], Bh[512], Bl[512];  // [row 0..127][kg 0..3]
  const int mt = blockIdx.x, nt = blockIdx.y;
  const int tid = threadIdx.x;
  const int lane = tid & 63, wave = tid >> 6;
  const int wm = wave >> 1, wn = wave & 1;
  const int m0 = mt * 128, n0 = nt * 128;
  f4v acc[4][4] = {};

  for (int ks = 0; ks < 16; ++ks) {
    const int k0 = ks * 32;
#pragma unroll
    for (int c = 0; c < 2; ++c) {
      int idx = c * 256 + tid;            // 0..511
      int r = idx >> 2, kg = idx & 3;
      int kgp = kg ^ (r & 3);
      int t_ = tok[m0 + r];
      const float* as = emb + (size_t)t_ * HID + k0 + kg * 8;
      float4 a0 = *(const float4*)as;
      float4 a1 = *(const float4*)(as + 4);
      float av[8] = {a0.x, a0.y, a0.z, a0.w, a1.x, a1.y, a1.z, a1.w};
      s8v ah, al;
#pragma unroll
      for (int j = 0; j < 8; ++j) {
        unsigned short h = f2bf_rne(av[j]);
        ah[j] = (short)h;
        al[j] = (short)f2bf_rne(av[j] - bf2f(h));
      }
      Ah[r * 4 + kgp] = ah;  Al[r * 4 + kgp] = al;
      const float* bs = w1 + (size_t)(n0 + r) * 1024 + k0 + kg * 8;
      float4 b0 = *(const float4*)bs;
      float4 b1v = *(const float4*)(bs + 4);
      float bv[8] = {b0.x, b0.y, b0.z, b0.w, b1v.x, b1v.y, b1v.z, b1v.w};
      s8v bh, bl;
#pragma unroll
      for (int j = 0; j < 8; ++j) {
        unsigned short h = f2bf_rne(bv[j]);
        bh[j] = (short)h;
        bl[j] = (short)f2bf_rne(bv[j] - bf2f(h));
      }
      Bh[r * 4 + kgp] = bh;  Bl[r * 4 + kgp] = bl;
    }
    __syncthreads();
    s8v afh[4], afl[4], bfh[4], bfl[4];
#pragma unroll
    for (int f = 0; f < 4; ++f) {
      int rA = wm * 64 + f * 16 + (lane & 15);
      afh[f] = Ah[rA * 4 + ((lane >> 4) ^ (rA & 3))];
      afl[f] = Al[rA * 4 + ((lane >> 4) ^ (rA & 3))];
      int rB = wn * 64 + f * 16 + (lane & 15);
      bfh[f] = Bh[rB * 4 + ((lane >> 4) ^ (rB & 3))];
      bfl[f] = Bl[rB * 4 + ((lane >> 4) ^ (rB & 3))];
    }
#pragma unroll
    for (int i = 0; i < 4; ++i)
#pragma unroll
      for (int j = 0; j < 4; ++j) {
        acc[i][j] = __builtin_amdgcn_mfma_f32_16x16x32_bf16(afh[i], bfh[j], acc[i][j], 0, 0, 0);
        acc[i][j] = __builtin_amdgcn_mfma_f32_16x16x32_bf16(afl[i], bfh[j], acc[i][j], 0, 0, 0);
        acc[i][j] = __builtin_amdgcn_mfma_f32_16x16x32_bf16(afh[i], bfl[j], acc[i][j], 0, 0, 0);
      }
    __syncthreads();
  }
#pragma unroll
  for (int j = 0; j < 4; ++j) {
    int col = n0 + wn * 64 + j * 16 + (lane & 15);
    float bias = b1[col];
#pragma unroll
    for (int i = 0; i < 4; ++i)
#pragma unroll
      for (int rg = 0; rg < 4; ++rg) {
        int row = m0 + wm * 64 + i * 16 + (lane >> 4) * 4 + rg;
        pre[(size_t)row * HID + col] = acc[i][j][rg] + bias;
      }
  }
}

// ---------------------------------------------------------------------------
// K2 v2: persistent scan. 128 WGs = 16 batches x 8 row-slices, 512 thr each.
// wh slice (64 rows x 512 cols, f32) lives in LDS, stored transposed [j][i]
// with i ^ (j&63) XOR swizzle -> conflict-free ds_read in the MAC loop.
// h exchanged via AGENT-scope atomics (per-access coherence, NO threadfence /
// L2 flush). Barrier: release fetch_add + acquire-LOAD polling, s_sleep(1).
// blockIdx swizzle: b = blk&15, ig = blk>>4  =>  the 8 WGs of batch b share
// blockIdx%8 == b%8 -> same XCD under round-robin dispatch (perf only).
// ---------------------------------------------------------------------------
__global__ __launch_bounds__(512, 2) void scan_kernel(
    const float* __restrict__ w1, const float* __restrict__ pre,
    float* hbuf, int* cnt,
    unsigned short* __restrict__ o_hi, unsigned short* __restrict__ o_lo,
    float* __restrict__ h_last_out) {
  __shared__ float wT[512 * 64];   // 128 KiB: wT[j*64 + (i ^ (j&63))] = wh[ig*64+i][j]
  __shared__ float hs[512];
  __shared__ float part[8 * 64];

  const int b  = blockIdx.x & 15;
  const int ig = blockIdx.x >> 4;
  const int tid = threadIdx.x;
  const int il = tid & 63, q = tid >> 6;

  // --- one-time: stage wh slice into LDS (transposed + swizzled) ---
  {
    const int i_loc = tid >> 3;            // 0..63 (8 threads per row)
    const int jseg  = (tid & 7) * 64;      // 64-col segment per thread
    const float* src = w1 + (size_t)(ig * 64 + i_loc) * 1024 + 512 + jseg;
#pragma unroll
    for (int j4 = 0; j4 < 16; ++j4) {
      float4 v = *(const float4*)(src + j4 * 4);
      int j0 = jseg + j4 * 4;
      wT[(j0 + 0) * 64 + (i_loc ^ ((j0 + 0) & 63))] = v.x;
      wT[(j0 + 1) * 64 + (i_loc ^ ((j0 + 1) & 63))] = v.y;
      wT[(j0 + 2) * 64 + (i_loc ^ ((j0 + 2) & 63))] = v.z;
      wT[(j0 + 3) * 64 + (i_loc ^ ((j0 + 3) & 63))] = v.w;
    }
  }
  __syncthreads();

  int* flag = cnt + b * 32;   // 128 B apart per batch

  for (int t = 0; t < T_STEPS; ++t) {
    const int cur = t & 1, nxt = cur ^ 1;
    // coherent read of full h for this batch into LDS
    hs[tid] = __hip_atomic_load(&hbuf[cur * (BATCH * HID) + b * HID + tid],
                                __ATOMIC_RELAXED, __HIP_MEMORY_SCOPE_AGENT);
    __syncthreads();

    float p = 0.f;
#pragma unroll
    for (int jj = 0; jj < 64; ++jj) {
      int j = q * 64 + jj;
      p += wT[j * 64 + (il ^ jj)] * hs[j];   // (j&63)==jj since q*64 is 64-aligned
    }
    part[q * 64 + il] = p;
    __syncthreads();

    if (tid < 64) {
      float s = 0.f;
#pragma unroll
      for (int pq = 0; pq < 8; ++pq) s += part[pq * 64 + il];
      const int m = t * BATCH + b;
      s += pre[(size_t)m * HID + ig * 64 + il];
      float hn = tanhf(s);
      __hip_atomic_store(&hbuf[nxt * (BATCH * HID) + b * HID + ig * 64 + il], hn,
                         __ATOMIC_RELAXED, __HIP_MEMORY_SCOPE_AGENT);
      unsigned short hi = f2bf_rne(hn);
      o_hi[(size_t)m * HID + ig * 64 + il] = hi;
      o_lo[(size_t)m * HID + ig * 64 + il] = f2bf_rne(hn - bf2f(hi));
      if (t == T_STEPS - 1) h_last_out[b * HID + ig * 64 + il] = hn;
    }
    __syncthreads();   // drains vmcnt -> all h stores complete before arrive

    if (tid == 0) {
      __hip_atomic_fetch_add(flag, 1, __ATOMIC_RELEASE, __HIP_MEMORY_SCOPE_AGENT);
      const int target = 8 * (t + 1);
      int spins = 0;
      while (__hip_atomic_load(flag, __ATOMIC_ACQUIRE, __HIP_MEMORY_SCOPE_AGENT) < target) {
        __builtin_amdgcn_s_sleep(1);
        if (++spins > (1 << 20)) break;   // safety: never wedge the harness
      }
    }
    __syncthreads();
  }
}

// ---------------------------------------------------------------------------
// K3: logits[m][v] = dec_b[v] + sum_j outputs[m][j] * dec_w[v][j]
// (unchanged from round 1)
// ---------------------------------------------------------------------------
__global__ __launch_bounds__(256, 2) void dec_gemm_kernel(
    const unsigned short* __restrict__ o_hi, const unsigned short* __restrict__ o_lo,
    const float* __restrict__ dec_w, const float* __restrict__ dec_b,
    float* __restrict__ out) {
  __shared__ s8v Ah[512], Al[512], Bh[512], Bl[512];
  const int mt = blockIdx.x;
  const int nt = blockIdx.y;
  const int tid = threadIdx.x;
  const int lane = tid & 63, wave = tid >> 6;
  const int wm = wave >> 1, wn = wave & 1;
  const int m0 = mt * 128, n0 = nt * 128;
  f4v acc[4][4] = {};

  for (int ks = 0; ks < 16; ++ks) {
    const int k0 = ks * 32;
#pragma unroll
    for (int c = 0; c < 2; ++c) {
      int idx = c * 256 + tid;
      int r = idx >> 2, kg = idx & 3;
      int kgp = kg ^ (r & 3);
      size_t aoff = (size_t)(m0 + r) * HID + k0 + kg * 8;
      Ah[r * 4 + kgp] = *(const s8v*)(o_hi + aoff);
      Al[r * 4 + kgp] = *(const s8v*)(o_lo + aoff);
      const float* bs = dec_w + (size_t)(n0 + r) * HID + k0 + kg * 8;
      float4 b0 = *(const float4*)bs;
      float4 b1v = *(const float4*)(bs + 4);
      float bv[8] = {b0.x, b0.y, b0.z, b0.w, b1v.x, b1v.y, b1v.z, b1v.w};
      s8v bh, bl;
#pragma unroll
      for (int j = 0; j < 8; ++j) {
        unsigned short h = f2bf_rne(bv[j]);
        bh[j] = (short)h;
        bl[j] = (short)f2bf_rne(bv[j] - bf2f(h));
      }
      Bh[r * 4 + kgp] = bh;  Bl[r * 4 + kgp] = bl;
    }
    __syncthreads();
    s8v afh[4], afl[4], bfh[4], bfl[4];
#pragma unroll
    for (int f = 0; f < 4; ++f) {
      int rA = wm * 64 + f * 16 + (lane & 15);
      afh[f] = Ah[rA * 4 + ((lane >> 4) ^ (rA & 3))];
      afl[f] = Al[rA * 4 + ((lane >> 4) ^ (rA & 3))];
      int rB = wn * 64 + f * 16 + (lane & 15);
      bfh[f] = Bh[rB * 4 + ((lane >> 4) ^ (rB & 3))];
      bfl[f] = Bl[rB * 4 + ((lane >> 4) ^ (rB & 3))];
    }
#pragma unroll
    for (int i = 0; i < 4; ++i)
#pragma unroll
      for (int j = 0; j < 4; ++j) {
        acc[i][j] = __builtin_amdgcn_mfma_f32_16x16x32_bf16(afh[i], bfh[j], acc[i][j], 0, 0, 0);
        acc[i][j] = __builtin_amdgcn_mfma_f32_16x16x32_bf16(afl[i], bfh[j], acc[i][j], 0, 0, 0);
        acc[i][j] = __builtin_amdgcn_mfma_f32_16x16x32_bf16(afh[i], bfl[j], acc[i][j], 0, 0, 0);
      }
    __syncthreads();
  }
#pragma unroll
  for (int j = 0; j < 4; ++j) {
    int col = n0 + wn * 64 + j * 16 + (lane & 15);
    float bias = dec_b[col];
#pragma unroll
    for (int i = 0; i < 4; ++i)
#pragma unroll
      for (int rg = 0; rg < 4; ++rg) {
        int row = m0 + wm * 64 + i * 16 + (lane >> 4) * 4 + rg;
        out[(size_t)row * VOCAB + col] = acc[i][j][rg] + bias;
      }
  }
}

// ---------------------------------------------------------------------------
// Workspace layout (bytes):
//   [0,        65536)   hbuf: 2 x 16 x 512 f32   (zeroed each call)
//   [65536,    67584)   cnt : 16 counters, 128 B apart (zeroed each call)
//   [1 MiB,    9 MiB)   pre : 4096 x 512 f32
//   [16 MiB,  20 MiB)   o_hi: 4096 x 512 bf16
//   [20 MiB,  24 MiB)   o_lo: 4096 x 512 bf16
// ---------------------------------------------------------------------------
extern "C" void kernel_launch(void* const* d_in, const int* in_sizes, int n_in,
                              void* d_out, int out_size, void* d_ws, size_t ws_size,
                              hipStream_t stream) {
  (void)in_sizes; (void)n_in; (void)out_size; (void)ws_size;
  const int*   tok   = (const int*)d_in[0];
  const float* emb   = (const float*)d_in[2];
  const float* w1    = (const float*)d_in[3];
  const float* b1    = (const float*)d_in[4];
  const float* dec_w = (const float*)d_in[5];
  const float* dec_b = (const float*)d_in[6];
  char* ws = (char*)d_ws;
  float* hbuf = (float*)(ws);
  int*   cnt  = (int*)(ws + 65536);
  float* pre  = (float*)(ws + (1u << 20));
  unsigned short* o_hi = (unsigned short*)(ws + 16u * (1u << 20));
  unsigned short* o_lo = (unsigned short*)(ws + 20u * (1u << 20));
  float* out = (float*)d_out;

  hipMemsetAsync(ws, 0, 67584, stream);
  pre_gemm_kernel<<<dim3(32, 4), dim3(256), 0, stream>>>(tok, emb, w1, b1, pre);
  scan_kernel<<<dim3(128), dim3(512), 0, stream>>>(
      w1, pre, hbuf, cnt, o_hi, o_lo, out + (size_t)M_TOT * VOCAB);
  dec_gemm_kernel<<<dim3(32, 250), dim3(256), 0, stream>>>(o_hi, o_lo, dec_w, dec_b, out);
}

// Round 3
// 925.438 us; speedup vs baseline: 5.0209x; 1.7404x over previous
//
#include <hip/hip_runtime.h>
#include <hip/hip_bf16.h>

// Problem constants (fixed by reference)
#define T_STEPS 256
#define BATCH   16
#define HID     512
#define VOCAB   32000
#define M_TOT   (T_STEPS * BATCH)   // 4096

typedef __attribute__((ext_vector_type(8))) short s8v;   // 8 bf16 (4 VGPRs)
typedef __attribute__((ext_vector_type(4))) float f4v;   // 4 f32 accum

__device__ __forceinline__ unsigned short f2bf_rne(float f) {
  unsigned u = __float_as_uint(f);
  unsigned r = u + 0x7fffu + ((u >> 16) & 1u);
  return (unsigned short)(r >> 16);
}
__device__ __forceinline__ float bf2f(unsigned short s) {
  return __uint_as_float(((unsigned)s) << 16);
}

// ---------------------------------------------------------------------------
// K1: pre[m][i] = b1[i] + sum_j emb[tok[m]][j] * w1[i][j]   (wx part of w1)
// (unchanged — passed, small cost)
// ---------------------------------------------------------------------------
__global__ __launch_bounds__(256, 2) void pre_gemm_kernel(
    const int* __restrict__ tok, const float* __restrict__ emb,
    const float* __restrict__ w1, const float* __restrict__ b1,
    float* __restrict__ pre) {
  __shared__ s8v Ah[512], Al[512], Bh[512], Bl[512];  // [row 0..127][kg 0..3]
  const int mt = blockIdx.x, nt = blockIdx.y;
  const int tid = threadIdx.x;
  const int lane = tid & 63, wave = tid >> 6;
  const int wm = wave >> 1, wn = wave & 1;
  const int m0 = mt * 128, n0 = nt * 128;
  f4v acc[4][4] = {};

  for (int ks = 0; ks < 16; ++ks) {
    const int k0 = ks * 32;
#pragma unroll
    for (int c = 0; c < 2; ++c) {
      int idx = c * 256 + tid;            // 0..511
      int r = idx >> 2, kg = idx & 3;
      int kgp = kg ^ (r & 3);
      int t_ = tok[m0 + r];
      const float* as = emb + (size_t)t_ * HID + k0 + kg * 8;
      float4 a0 = *(const float4*)as;
      float4 a1 = *(const float4*)(as + 4);
      float av[8] = {a0.x, a0.y, a0.z, a0.w, a1.x, a1.y, a1.z, a1.w};
      s8v ah, al;
#pragma unroll
      for (int j = 0; j < 8; ++j) {
        unsigned short h = f2bf_rne(av[j]);
        ah[j] = (short)h;
        al[j] = (short)f2bf_rne(av[j] - bf2f(h));
      }
      Ah[r * 4 + kgp] = ah;  Al[r * 4 + kgp] = al;
      const float* bs = w1 + (size_t)(n0 + r) * 1024 + k0 + kg * 8;
      float4 b0 = *(const float4*)bs;
      float4 b1v = *(const float4*)(bs + 4);
      float bv[8] = {b0.x, b0.y, b0.z, b0.w, b1v.x, b1v.y, b1v.z, b1v.w};
      s8v bh, bl;
#pragma unroll
      for (int j = 0; j < 8; ++j) {
        unsigned short h = f2bf_rne(bv[j]);
        bh[j] = (short)h;
        bl[j] = (short)f2bf_rne(bv[j] - bf2f(h));
      }
      Bh[r * 4 + kgp] = bh;  Bl[r * 4 + kgp] = bl;
    }
    __syncthreads();
    s8v afh[4], afl[4], bfh[4], bfl[4];
#pragma unroll
    for (int f = 0; f < 4; ++f) {
      int rA = wm * 64 + f * 16 + (lane & 15);
      afh[f] = Ah[rA * 4 + ((lane >> 4) ^ (rA & 3))];
      afl[f] = Al[rA * 4 + ((lane >> 4) ^ (rA & 3))];
      int rB = wn * 64 + f * 16 + (lane & 15);
      bfh[f] = Bh[rB * 4 + ((lane >> 4) ^ (rB & 3))];
      bfl[f] = Bl[rB * 4 + ((lane >> 4) ^ (rB & 3))];
    }
#pragma unroll
    for (int i = 0; i < 4; ++i)
#pragma unroll
      for (int j = 0; j < 4; ++j) {
        acc[i][j] = __builtin_amdgcn_mfma_f32_16x16x32_bf16(afh[i], bfh[j], acc[i][j], 0, 0, 0);
        acc[i][j] = __builtin_amdgcn_mfma_f32_16x16x32_bf16(afl[i], bfh[j], acc[i][j], 0, 0, 0);
        acc[i][j] = __builtin_amdgcn_mfma_f32_16x16x32_bf16(afh[i], bfl[j], acc[i][j], 0, 0, 0);
      }
    __syncthreads();
  }
#pragma unroll
  for (int j = 0; j < 4; ++j) {
    int col = n0 + wn * 64 + j * 16 + (lane & 15);
    float bias = b1[col];
#pragma unroll
    for (int i = 0; i < 4; ++i)
#pragma unroll
      for (int rg = 0; rg < 4; ++rg) {
        int row = m0 + wm * 64 + i * 16 + (lane >> 4) * 4 + rg;
        pre[(size_t)row * HID + col] = acc[i][j][rg] + bias;
      }
  }
}

// ---------------------------------------------------------------------------
// K2 v3: barrier-free persistent scan.
// 128 WGs = 16 row-slices (32 rows each) x 8 batch-pairs, 512 threads.
// wh slice (32x512 f32 = 64 KiB) in LDS, row-major, 16B-unit XOR swizzle
// (u ^ (row&7)) -> conflict-free ds_read_b128 in the MAC.
// h exchange: hbuf is u64[2][16][512] of (tag<<32 | f32bits). Producers do ONE
// relaxed AGENT 8B store; consumers spin on relaxed 8B loads until tag==t.
// Data IS the flag: no fences, no fetch_add, no inter-WG barrier.
// Lap-safety: overwriting parity slot at t+2 requires having READ tag-(t+2)
// values from every WG, which proves they consumed step t. 2 buffers suffice.
// ---------------------------------------------------------------------------
__global__ __launch_bounds__(512) void scan_kernel(
    const float* __restrict__ w1, const float* __restrict__ pre,
    unsigned long long* hbuf,
    unsigned short* __restrict__ o_hi, unsigned short* __restrict__ o_lo,
    float* __restrict__ h_last_out) {
  __shared__ float wLds[16384];      // 64 KiB swizzled wh slice
  __shared__ float hs[2][512];       // h for the 2 batches
  __shared__ float part[2][528];     // [batch][s*33 + i], padded stride 33

  const int bp = blockIdx.x & 7;     // batch pair 0..7 (same %8 -> same XCD)
  const int sg = blockIdx.x >> 3;    // row slice 0..15
  const int b0 = bp * 2, b1 = b0 + 1;
  const int tid = threadIdx.x;

  // --- one-time: stage wh slice, row-major + 16B-unit swizzle ---
  // logical: row r (0..31), unit u (0..127) = w1[(sg*32+r)*1024 + 512 + u*4 ..+3]
  // physical float idx: r*512 + (u>>3)*32 + (((u&7) ^ (r&7)) << 2)
#pragma unroll
  for (int k = 0; k < 8; ++k) {
    int uid = k * 512 + tid;         // 0..4095
    int r = uid >> 7, u = uid & 127;
    float4 v = *(const float4*)(w1 + (size_t)(sg * 32 + r) * 1024 + 512 + u * 4);
    int dst = r * 512 + (u >> 3) * 32 + (((u & 7) ^ (r & 7)) << 2);
    *(float4*)(&wLds[dst]) = v;
  }
  __syncthreads();

  const int i = tid & 31, s = tid >> 5;      // output row i, j-segment s (32 j's)
  const int rowbase = i * 512 + s * 32;
  const int isw = i & 7;

  for (int t = 0; t < T_STEPS; ++t) {
    const int cur = t & 1, nxt = cur ^ 1;

    // prefetch pre for the finisher threads (independent of h -> hides under poll)
    float pv = 0.f;
    if (tid < 64) {
      int bl = tid >> 5, ii = tid & 31;
      pv = pre[(size_t)(t * BATCH + b0 + bl) * HID + sg * 32 + ii];
    }

    // --- poll: thread tid owns element j=tid for both batches ---
    unsigned long long* p0 = hbuf + ((size_t)cur * BATCH + b0) * HID + tid;
    unsigned long long* p1 = hbuf + ((size_t)cur * BATCH + b1) * HID + tid;
    unsigned long long e0 = __hip_atomic_load(p0, __ATOMIC_RELAXED, __HIP_MEMORY_SCOPE_AGENT);
    unsigned long long e1 = __hip_atomic_load(p1, __ATOMIC_RELAXED, __HIP_MEMORY_SCOPE_AGENT);
    int spins = 0;
    while ((unsigned)(e0 >> 32) != (unsigned)t || (unsigned)(e1 >> 32) != (unsigned)t) {
      __builtin_amdgcn_s_sleep(1);
      if ((unsigned)(e0 >> 32) != (unsigned)t)
        e0 = __hip_atomic_load(p0, __ATOMIC_RELAXED, __HIP_MEMORY_SCOPE_AGENT);
      if ((unsigned)(e1 >> 32) != (unsigned)t)
        e1 = __hip_atomic_load(p1, __ATOMIC_RELAXED, __HIP_MEMORY_SCOPE_AGENT);
      if (++spins > (1 << 20)) break;   // safety valve, never hit in practice
    }
    hs[0][tid] = __uint_as_float((unsigned)e0);
    hs[1][tid] = __uint_as_float((unsigned)e1);
    __syncthreads();   // sync #1: hs ready (also orders part-overwrite vs prev reduce)

    // --- MAC: 8 swizzled b128 wh units x (4 f32 x 2 batches) ---
    float a0 = 0.f, a1 = 0.f;
#pragma unroll
    for (int u = 0; u < 8; ++u) {
      float4 w = *(const float4*)(&wLds[rowbase + ((u ^ isw) << 2)]);
      float4 h0 = *(const float4*)(&hs[0][s * 32 + (u << 2)]);
      float4 h1 = *(const float4*)(&hs[1][s * 32 + (u << 2)]);
      a0 += w.x * h0.x + w.y * h0.y + w.z * h0.z + w.w * h0.w;
      a1 += w.x * h1.x + w.y * h1.y + w.z * h1.z + w.w * h1.w;
    }
    part[0][s * 33 + i] = a0;
    part[1][s * 33 + i] = a1;
    __syncthreads();   // sync #2: part ready

    // --- finish: 64 threads = 2 batches x 32 rows ---
    if (tid < 64) {
      int bl = tid >> 5, ii = tid & 31;
      float ssum = 0.f;
#pragma unroll
      for (int ss = 0; ss < 16; ++ss) ssum += part[bl][ss * 33 + ii];
      ssum += pv;
      float hn = tanhf(ssum);
      int b = b0 + bl;
      // critical-path store FIRST: value+tag in one 8B atomic
      unsigned long long ev = ((unsigned long long)(unsigned)(t + 1) << 32) |
                              (unsigned long long)__float_as_uint(hn);
      __hip_atomic_store(hbuf + ((size_t)nxt * BATCH + b) * HID + sg * 32 + ii, ev,
                         __ATOMIC_RELAXED, __HIP_MEMORY_SCOPE_AGENT);
      // off-path outputs
      int m = t * BATCH + b;
      unsigned short hi_ = f2bf_rne(hn);
      o_hi[(size_t)m * HID + sg * 32 + ii] = hi_;
      o_lo[(size_t)m * HID + sg * 32 + ii] = f2bf_rne(hn - bf2f(hi_));
      if (t == T_STEPS - 1) h_last_out[(size_t)b * HID + sg * 32 + ii] = hn;
    }
    // no third sync needed: next iteration's sync #1 orders part overwrite
  }
}

// ---------------------------------------------------------------------------
// K3: logits[m][v] = dec_b[v] + sum_j outputs[m][j] * dec_w[v][j]
// (unchanged)
// ---------------------------------------------------------------------------
__global__ __launch_bounds__(256, 2) void dec_gemm_kernel(
    const unsigned short* __restrict__ o_hi, const unsigned short* __restrict__ o_lo,
    const float* __restrict__ dec_w, const float* __restrict__ dec_b,
    float* __restrict__ out) {
  __shared__ s8v Ah[512], Al[512], Bh[512], Bl[512];
  const int mt = blockIdx.x;
  const int nt = blockIdx.y;
  const int tid = threadIdx.x;
  const int lane = tid & 63, wave = tid >> 6;
  const int wm = wave >> 1, wn = wave & 1;
  const int m0 = mt * 128, n0 = nt * 128;
  f4v acc[4][4] = {};

  for (int ks = 0; ks < 16; ++ks) {
    const int k0 = ks * 32;
#pragma unroll
    for (int c = 0; c < 2; ++c) {
      int idx = c * 256 + tid;
      int r = idx >> 2, kg = idx & 3;
      int kgp = kg ^ (r & 3);
      size_t aoff = (size_t)(m0 + r) * HID + k0 + kg * 8;
      Ah[r * 4 + kgp] = *(const s8v*)(o_hi + aoff);
      Al[r * 4 + kgp] = *(const s8v*)(o_lo + aoff);
      const float* bs = dec_w + (size_t)(n0 + r) * HID + k0 + kg * 8;
      float4 b0 = *(const float4*)bs;
      float4 b1v = *(const float4*)(bs + 4);
      float bv[8] = {b0.x, b0.y, b0.z, b0.w, b1v.x, b1v.y, b1v.z, b1v.w};
      s8v bh, bl;
#pragma unroll
      for (int j = 0; j < 8; ++j) {
        unsigned short h = f2bf_rne(bv[j]);
        bh[j] = (short)h;
        bl[j] = (short)f2bf_rne(bv[j] - bf2f(h));
      }
      Bh[r * 4 + kgp] = bh;  Bl[r * 4 + kgp] = bl;
    }
    __syncthreads();
    s8v afh[4], afl[4], bfh[4], bfl[4];
#pragma unroll
    for (int f = 0; f < 4; ++f) {
      int rA = wm * 64 + f * 16 + (lane & 15);
      afh[f] = Ah[rA * 4 + ((lane >> 4) ^ (rA & 3))];
      afl[f] = Al[rA * 4 + ((lane >> 4) ^ (rA & 3))];
      int rB = wn * 64 + f * 16 + (lane & 15);
      bfh[f] = Bh[rB * 4 + ((lane >> 4) ^ (rB & 3))];
      bfl[f] = Bl[rB * 4 + ((lane >> 4) ^ (rB & 3))];
    }
#pragma unroll
    for (int i = 0; i < 4; ++i)
#pragma unroll
      for (int j = 0; j < 4; ++j) {
        acc[i][j] = __builtin_amdgcn_mfma_f32_16x16x32_bf16(afh[i], bfh[j], acc[i][j], 0, 0, 0);
        acc[i][j] = __builtin_amdgcn_mfma_f32_16x16x32_bf16(afl[i], bfh[j], acc[i][j], 0, 0, 0);
        acc[i][j] = __builtin_amdgcn_mfma_f32_16x16x32_bf16(afh[i], bfl[j], acc[i][j], 0, 0, 0);
      }
    __syncthreads();
  }
#pragma unroll
  for (int j = 0; j < 4; ++j) {
    int col = n0 + wn * 64 + j * 16 + (lane & 15);
    float bias = dec_b[col];
#pragma unroll
    for (int i = 0; i < 4; ++i)
#pragma unroll
      for (int rg = 0; rg < 4; ++rg) {
        int row = m0 + wm * 64 + i * 16 + (lane >> 4) * 4 + rg;
        out[(size_t)row * VOCAB + col] = acc[i][j][rg] + bias;
      }
  }
}

// ---------------------------------------------------------------------------
// Workspace layout (bytes):
//   [0,       131072)   hbuf: u64[2][16][512] (tag|f32)  (zeroed each call)
//   [1 MiB,    9 MiB)   pre : 4096 x 512 f32
//   [16 MiB,  20 MiB)   o_hi: 4096 x 512 bf16
//   [20 MiB,  24 MiB)   o_lo: 4096 x 512 bf16
// ---------------------------------------------------------------------------
extern "C" void kernel_launch(void* const* d_in, const int* in_sizes, int n_in,
                              void* d_out, int out_size, void* d_ws, size_t ws_size,
                              hipStream_t stream) {
  (void)in_sizes; (void)n_in; (void)out_size; (void)ws_size;
  const int*   tok   = (const int*)d_in[0];
  const float* emb   = (const float*)d_in[2];
  const float* w1    = (const float*)d_in[3];
  const float* b1    = (const float*)d_in[4];
  const float* dec_w = (const float*)d_in[5];
  const float* dec_b = (const float*)d_in[6];
  char* ws = (char*)d_ws;
  unsigned long long* hbuf = (unsigned long long*)(ws);
  float* pre  = (float*)(ws + (1u << 20));
  unsigned short* o_hi = (unsigned short*)(ws + 16u * (1u << 20));
  unsigned short* o_lo = (unsigned short*)(ws + 20u * (1u << 20));
  float* out = (float*)d_out;

  hipMemsetAsync(ws, 0, 131072, stream);   // tag=0, h0=0
  pre_gemm_kernel<<<dim3(32, 4), dim3(256), 0, stream>>>(tok, emb, w1, b1, pre);
  scan_kernel<<<dim3(128), dim3(512), 0, stream>>>(
      w1, pre, hbuf, o_hi, o_lo, out + (size_t)M_TOT * VOCAB);
  dec_gemm_kernel<<<dim3(32, 250), dim3(256), 0, stream>>>(o_hi, o_lo, dec_w, dec_b, out);
}